// Round 2
// baseline (741.342 us; speedup 1.0000x reference)
//
#include <hip/hip_runtime.h>

typedef _Float16 f16;
typedef _Float16 f16x4 __attribute__((ext_vector_type(4)));
typedef _Float16 f16x8 __attribute__((ext_vector_type(8)));
typedef float    f32x4 __attribute__((ext_vector_type(4)));

// ---------------------------------------------------------------------------
// pack x: [B,C,T,F] fp32 -> xi f16 [G][m = b*500+t][i = gf*64+c]
// ---------------------------------------------------------------------------
__global__ void k_pack_x(const float* __restrict__ x, f16* __restrict__ xi) {
  const int tc = blockIdx.x;   // 0..124, 4 timesteps each
  const int b  = blockIdx.y;   // 0..15
  const int t0 = tc * 4;
  const int tid = threadIdx.x; // 256
  __shared__ __align__(16) float lds[64 * 133];  // [c][t*33+f], padded
  #pragma unroll
  for (int it = 0; it < 32; it++) {
    int flat = it * 256 + tid;
    int c = flat >> 7;
    int t = (flat >> 5) & 3;
    int f = flat & 31;
    lds[c * 133 + t * 33 + f] =
        x[(((size_t)b * 64 + c) * 500 + t0 + t) * 32 + f];
  }
  __syncthreads();
  const int w = tid >> 6, l = tid & 63;
  #pragma unroll
  for (int rr = 0; rr < 8; rr++) {
    int row = w * 8 + rr;            // 0..31 = (g,t)
    int g = row >> 2, t = row & 3;
    f16x4 v;
    #pragma unroll
    for (int e = 0; e < 4; e++) {
      int i = l * 4 + e;             // i = gf*64 + c
      int gf = i >> 6, c = i & 63;
      v[e] = (f16)lds[c * 133 + t * 33 + g * 4 + gf];
    }
    *(f16x4*)&xi[((size_t)g * 8000 + (size_t)b * 500 + t0 + t) * 256 + l * 4] = v;
  }
}

// ---------------------------------------------------------------------------
// pack W_ih: fp32 -> f16, same layout [G][768][256]
// ---------------------------------------------------------------------------
__global__ void k_pack_wih(const float* __restrict__ w, f16* __restrict__ wh) {
  size_t i0 = ((size_t)blockIdx.x * 256 + threadIdx.x) * 8;
  f32x4 a = *(const f32x4*)(w + i0);
  f32x4 b = *(const f32x4*)(w + i0 + 4);
  f16x8 v;
  v[0]=(f16)a[0]; v[1]=(f16)a[1]; v[2]=(f16)a[2]; v[3]=(f16)a[3];
  v[4]=(f16)b[0]; v[5]=(f16)b[1]; v[6]=(f16)b[2]; v[7]=(f16)b[3];
  *(f16x8*)(wh + i0) = v;
}

// ---------------------------------------------------------------------------
// pack W_hh into MFMA B-fragment layout (f16):
// wp frag index ((g*48 + nt)*8 + kt)*64 + l, elem e:
//   = W_hh[g][nt*16 + (l&15)][kt*32 + (l>>4)*8 + e]
// ---------------------------------------------------------------------------
__global__ void k_pack_whh(const float* __restrict__ w, f16* __restrict__ wp) {
  const int nt = blockIdx.x;   // 0..47
  const int g  = blockIdx.y;   // 0..7
  const int tid = threadIdx.x; // 512
  const int kt = tid >> 6, l = tid & 63;
  const int row = nt * 16 + (l & 15);
  const int k0  = kt * 32 + ((l >> 4) & 3) * 8;
  const float* src = w + ((size_t)g * 768 + row) * 256 + k0;
  f16x8 v;
  #pragma unroll
  for (int e = 0; e < 8; e++) v[e] = (f16)src[e];
  *(f16x8*)&wp[((((size_t)g * 48 + nt) * 8 + kt) * 64 + l) * 8] = v;
}

// ---------------------------------------------------------------------------
// ih GEMM: per g, C[m][o] = sum_i xi[m][i] * Wih[o][i] + bias_ih[o]
// tile M=64 x N=128, BK=64, 4 waves, mfma_f32_16x16x32_f16, XOR-swizzled LDS.
// ---------------------------------------------------------------------------
__global__ __launch_bounds__(256) void k_gemm(const f16* __restrict__ xi,
                                              const f16* __restrict__ wih,
                                              const float* __restrict__ bias,
                                              f16* __restrict__ ih) {
  const int mt = blockIdx.x;   // 0..124
  const int nt = blockIdx.y;   // 0..5
  const int g  = blockIdx.z;   // 0..7
  const int tid = threadIdx.x;
  const int w = tid >> 6, l = tid & 63;
  __shared__ __align__(16) f16 Als[64 * 64];
  __shared__ __align__(16) f16 Bls[128 * 64];
  f32x4 zero = {0.f, 0.f, 0.f, 0.f};
  f32x4 acc[4][2];
  #pragma unroll
  for (int mi = 0; mi < 4; mi++)
    #pragma unroll
    for (int ni = 0; ni < 2; ni++) acc[mi][ni] = zero;

  const int arow = tid >> 2, aq = tid & 3;
  const int brow = tid >> 1, bq = tid & 1;
  for (int kk = 0; kk < 4; kk++) {
    const f16* asrc = xi + ((size_t)g * 8000 + mt * 64 + arow) * 256 + kk * 64 + aq * 16;
    f16x8 a0 = *(const f16x8*)asrc;
    f16x8 a1 = *(const f16x8*)(asrc + 8);
    *(f16x8*)&Als[arow * 64 + ((aq * 2 + 0) ^ (arow & 7)) * 8] = a0;
    *(f16x8*)&Als[arow * 64 + ((aq * 2 + 1) ^ (arow & 7)) * 8] = a1;
    const f16* bsrc = wih + ((size_t)g * 768 + nt * 128 + brow) * 256 + kk * 64 + bq * 32;
    #pragma unroll
    for (int jj = 0; jj < 4; jj++) {
      f16x8 v = *(const f16x8*)(bsrc + jj * 8);
      *(f16x8*)&Bls[brow * 64 + ((bq * 4 + jj) ^ (brow & 7)) * 8] = v;
    }
    __syncthreads();
    #pragma unroll
    for (int ks = 0; ks < 2; ks++) {
      f16x8 af[4], bf[2];
      #pragma unroll
      for (int mi = 0; mi < 4; mi++) {
        int r = mi * 16 + (l & 15);
        af[mi] = *(const f16x8*)&Als[r * 64 + ((ks * 4 + (l >> 4)) ^ (r & 7)) * 8];
      }
      #pragma unroll
      for (int ni = 0; ni < 2; ni++) {
        int r = w * 32 + ni * 16 + (l & 15);
        bf[ni] = *(const f16x8*)&Bls[r * 64 + ((ks * 4 + (l >> 4)) ^ (r & 7)) * 8];
      }
      #pragma unroll
      for (int mi = 0; mi < 4; mi++)
        #pragma unroll
        for (int ni = 0; ni < 2; ni++)
          acc[mi][ni] = __builtin_amdgcn_mfma_f32_16x16x32_f16(af[mi], bf[ni], acc[mi][ni], 0, 0, 0);
    }
    __syncthreads();
  }
  #pragma unroll
  for (int ni = 0; ni < 2; ni++) {
    int col = nt * 128 + w * 32 + ni * 16 + (l & 15);
    float bs = bias[g * 768 + col];
    #pragma unroll
    for (int mi = 0; mi < 4; mi++) {
      int m0 = mt * 64 + mi * 16 + (l >> 4) * 4;
      #pragma unroll
      for (int e = 0; e < 4; e++) {
        ih[((size_t)g * 8000 + m0 + e) * 768 + col] = (f16)(acc[mi][ni][e] + bs);
      }
    }
  }
}

// ---------------------------------------------------------------------------
// recurrence v2: one block (512 thr, 8 waves) per (b,g) chain.
// W_hh lives in 192 VGPR/thread as MFMA B-fragments. Per step:
//   phase1: broadcast-A mfma  hh[768] = W_hh * h   (48 Ntiles x 8 Ktiles)
//   phase2: threads 0..255 compute gates, update h.
// ---------------------------------------------------------------------------
__global__ __launch_bounds__(512, 2) void k_recur(const f16* __restrict__ ih,
                                                  const f16* __restrict__ wp,
                                                  const float* __restrict__ bias_hh,
                                                  f16* __restrict__ hs,
                                                  float* __restrict__ hlast) {
  const int g = blockIdx.x;    // 0..7
  const int b = blockIdx.y;    // 0..15
  const int tid = threadIdx.x;
  const int w = tid >> 6, l = tid & 63;
  __shared__ __align__(16) f16 hsm[256];
  __shared__ __align__(16) float hhx[768];

  // load this thread's 48 B-fragments (192 VGPRs)
  f16x8 bf[6][8];
  {
    const f16x8* wsrc = (const f16x8*)wp + (size_t)g * 48 * 8 * 64;
    #pragma unroll
    for (int j = 0; j < 6; j++)
      #pragma unroll
      for (int kt = 0; kt < 8; kt++)
        bf[j][kt] = wsrc[(size_t)((w * 6 + j) * 8 + kt) * 64 + l];
  }

  float bh0 = 0.f, bh1 = 0.f, bh2 = 0.f, hreg = 0.f;
  if (tid < 256) {
    bh0 = bias_hh[g * 768 + tid];
    bh1 = bias_hh[g * 768 + 256 + tid];
    bh2 = bias_hh[g * 768 + 512 + tid];
    hsm[tid] = (f16)0.f;
  }
  const f16* ihb = ih + ((size_t)g * 8000 + (size_t)b * 500) * 768;
  f16* hsp = hs + (size_t)(b * 8 + g) * 500 * 256;
  f16 c0 = (f16)0.f, c1 = (f16)0.f, c2 = (f16)0.f;
  if (tid < 256) { c0 = ihb[tid]; c1 = ihb[256 + tid]; c2 = ihb[512 + tid]; }
  const int koff = ((l >> 4) & 3) * 8;   // f16 element offset within a ktile
  __syncthreads();

  for (int t = 0; t < 500; t++) {
    // prefetch next step's ih into regs (consumed after phase2)
    f16 n0 = c0, n1 = c1, n2 = c2;
    if (tid < 256 && t + 1 < 500) {
      const f16* p = ihb + (size_t)(t + 1) * 768;
      n0 = p[tid]; n1 = p[256 + tid]; n2 = p[512 + tid];
    }
    // phase 1: hh = W_hh * h via broadcast-A MFMA, 2 passes of 3 N-tiles
    #pragma unroll
    for (int half = 0; half < 2; half++) {
      f32x4 a0 = {0.f, 0.f, 0.f, 0.f};
      f32x4 a1 = a0, a2 = a0;
      #pragma unroll
      for (int hb = 0; hb < 2; hb++) {
        f16x8 hf0 = *(const f16x8*)&hsm[(hb * 4 + 0) * 32 + koff];
        f16x8 hf1 = *(const f16x8*)&hsm[(hb * 4 + 1) * 32 + koff];
        f16x8 hf2 = *(const f16x8*)&hsm[(hb * 4 + 2) * 32 + koff];
        f16x8 hf3 = *(const f16x8*)&hsm[(hb * 4 + 3) * 32 + koff];
        a0 = __builtin_amdgcn_mfma_f32_16x16x32_f16(hf0, bf[half * 3 + 0][hb * 4 + 0], a0, 0, 0, 0);
        a1 = __builtin_amdgcn_mfma_f32_16x16x32_f16(hf0, bf[half * 3 + 1][hb * 4 + 0], a1, 0, 0, 0);
        a2 = __builtin_amdgcn_mfma_f32_16x16x32_f16(hf0, bf[half * 3 + 2][hb * 4 + 0], a2, 0, 0, 0);
        a0 = __builtin_amdgcn_mfma_f32_16x16x32_f16(hf1, bf[half * 3 + 0][hb * 4 + 1], a0, 0, 0, 0);
        a1 = __builtin_amdgcn_mfma_f32_16x16x32_f16(hf1, bf[half * 3 + 1][hb * 4 + 1], a1, 0, 0, 0);
        a2 = __builtin_amdgcn_mfma_f32_16x16x32_f16(hf1, bf[half * 3 + 2][hb * 4 + 1], a2, 0, 0, 0);
        a0 = __builtin_amdgcn_mfma_f32_16x16x32_f16(hf2, bf[half * 3 + 0][hb * 4 + 2], a0, 0, 0, 0);
        a1 = __builtin_amdgcn_mfma_f32_16x16x32_f16(hf2, bf[half * 3 + 1][hb * 4 + 2], a1, 0, 0, 0);
        a2 = __builtin_amdgcn_mfma_f32_16x16x32_f16(hf2, bf[half * 3 + 2][hb * 4 + 2], a2, 0, 0, 0);
        a0 = __builtin_amdgcn_mfma_f32_16x16x32_f16(hf3, bf[half * 3 + 0][hb * 4 + 3], a0, 0, 0, 0);
        a1 = __builtin_amdgcn_mfma_f32_16x16x32_f16(hf3, bf[half * 3 + 1][hb * 4 + 3], a1, 0, 0, 0);
        a2 = __builtin_amdgcn_mfma_f32_16x16x32_f16(hf3, bf[half * 3 + 2][hb * 4 + 3], a2, 0, 0, 0);
      }
      if (l < 16) {
        hhx[(w * 6 + half * 3 + 0) * 16 + l] = a0[0];
        hhx[(w * 6 + half * 3 + 1) * 16 + l] = a1[0];
        hhx[(w * 6 + half * 3 + 2) * 16 + l] = a2[0];
      }
    }
    __syncthreads();
    // phase 2: gates on threads 0..255
    if (tid < 256) {
      float rh = hhx[tid] + bh0;
      float zh = hhx[256 + tid] + bh1;
      float nh = hhx[512 + tid] + bh2;
      float r = 1.f / (1.f + __expf(-((float)c0 + rh)));
      float z = 1.f / (1.f + __expf(-((float)c1 + zh)));
      float nx = (float)c2 + r * nh;
      float n = 2.f / (1.f + __expf(-2.f * nx)) - 1.f;
      float hn = (1.f - z) * n + z * hreg;
      hreg = hn;
      hsm[tid] = (f16)hn;
      hsp[(size_t)t * 256 + tid] = (f16)hn;
    }
    __syncthreads();
    c0 = n0; c1 = n1; c2 = n2;
  }
  if (tid < 256) hlast[(size_t)(b * 8 + g) * 256 + tid] = hreg;
}

// ---------------------------------------------------------------------------
// un-transpose: hs f16 [b*8+g][t][o] -> out fp32 [b][och][t][f], f=g*4+gf, o=gf*64+och
// ---------------------------------------------------------------------------
__global__ void k_untr(const f16* __restrict__ hs, float* __restrict__ out) {
  const int tc = blockIdx.x;   // 0..62 (8 t each, tail 4)
  const int b  = blockIdx.y;   // 0..15
  const int t0 = tc * 8;
  const int tid = threadIdx.x; // 256
  __shared__ __align__(16) f16 lds[8 * 8 * 260];  // [(tt*8+g)*260 + o]
  {
    const int row = tid >> 2, q = tid & 3;  // row: 64 = (g,tt)
    const int g = row >> 3, tt = row & 7;
    if (t0 + tt < 500) {
      const f16* src = hs + (((size_t)b * 8 + g) * 500 + t0 + tt) * 256 + q * 64;
      #pragma unroll
      for (int jj = 0; jj < 16; jj++) {
        *(f16x4*)&lds[(tt * 8 + g) * 260 + q * 64 + jj * 4] = *(const f16x4*)(src + jj * 4);
      }
    }
  }
  __syncthreads();
  const int w = tid >> 6, l = tid & 63;
  const int tt2 = w * 2 + (l >> 5);
  const int f = l & 31;
  const int gg = f >> 2, gf = f & 3;
  if (t0 + tt2 < 500) {
    float* dst = out + (((size_t)b * 64) * 500 + t0 + tt2) * 32 + f;
    const f16* srcl = &lds[(tt2 * 8 + gg) * 260 + gf * 64];
    #pragma unroll 4
    for (int och = 0; och < 64; och++) {
      dst[(size_t)och * 500 * 32] = (float)srcl[och];
    }
  }
}

// ---------------------------------------------------------------------------
extern "C" void kernel_launch(void* const* d_in, const int* in_sizes, int n_in,
                              void* d_out, int out_size, void* d_ws, size_t ws_size,
                              hipStream_t stream) {
  const float* x   = (const float*)d_in[0];
  const float* wih = (const float*)d_in[1];
  const float* whh = (const float*)d_in[2];
  const float* bih = (const float*)d_in[3];
  const float* bhh = (const float*)d_in[4];
  float* out   = (float*)d_out;
  float* hlast = out + 16384000;   // B*64*T*F

  char* ws = (char*)d_ws;
  f16* ih_h  = (f16*)(ws);                 //  98,304,000 B : [8][8000][768]
  f16* xi_h  = (f16*)(ws + 98304000);      //  32,768,000 B : [8][8000][256]
  f16* wih_h = (f16*)(ws + 131072000);     //   3,145,728 B : [8][768][256]
  f16* whh_p = (f16*)(ws + 134217728);     //   3,145,728 B : packed B-frags
  f16* hs_h  = (f16*)(ws + 137363456);     //  32,768,000 B : [128][500][256]

  k_pack_x  <<<dim3(125, 16), 256, 0, stream>>>(x, xi_h);
  k_pack_wih<<<768, 256, 0, stream>>>(wih, wih_h);
  k_pack_whh<<<dim3(48, 8), 512, 0, stream>>>(whh, whh_p);
  k_gemm    <<<dim3(125, 6, 8), 256, 0, stream>>>(xi_h, wih_h, bih, ih_h);
  k_recur   <<<dim3(8, 16), 512, 0, stream>>>(ih_h, whh_p, bhh, hs_h, hlast);
  k_untr    <<<dim3(63, 16), 256, 0, stream>>>(hs_h, out);
}

// Round 3
// 707.037 us; speedup vs baseline: 1.0485x; 1.0485x over previous
//
#include <hip/hip_runtime.h>

typedef _Float16 f16;
typedef _Float16 f16x4 __attribute__((ext_vector_type(4)));
typedef _Float16 f16x8 __attribute__((ext_vector_type(8)));
typedef float    f32x4 __attribute__((ext_vector_type(4)));

#if defined(__has_builtin)
#if __has_builtin(__builtin_amdgcn_fdot2)
#define HAVE_FDOT2 1
#endif
#endif

__device__ __forceinline__ float dot8(f16x8 a, f16x8 b, float acc) {
#ifdef HAVE_FDOT2
  acc = __builtin_amdgcn_fdot2(__builtin_shufflevector(a, a, 0, 1),
                               __builtin_shufflevector(b, b, 0, 1), acc, false);
  acc = __builtin_amdgcn_fdot2(__builtin_shufflevector(a, a, 2, 3),
                               __builtin_shufflevector(b, b, 2, 3), acc, false);
  acc = __builtin_amdgcn_fdot2(__builtin_shufflevector(a, a, 4, 5),
                               __builtin_shufflevector(b, b, 4, 5), acc, false);
  acc = __builtin_amdgcn_fdot2(__builtin_shufflevector(a, a, 6, 7),
                               __builtin_shufflevector(b, b, 6, 7), acc, false);
#else
  #pragma unroll
  for (int i = 0; i < 8; i++) acc += (float)a[i] * (float)b[i];
#endif
  return acc;
}

// ---------------------------------------------------------------------------
// pack x: [B,C,T,F] fp32 -> xi f16 [G][m = b*500+t][i = gf*64+c]
// ---------------------------------------------------------------------------
__global__ void k_pack_x(const float* __restrict__ x, f16* __restrict__ xi) {
  const int tc = blockIdx.x;   // 0..124, 4 timesteps each
  const int b  = blockIdx.y;   // 0..15
  const int t0 = tc * 4;
  const int tid = threadIdx.x; // 256
  __shared__ __align__(16) float lds[64 * 133];  // [c][t*33+f], padded
  #pragma unroll
  for (int it = 0; it < 32; it++) {
    int flat = it * 256 + tid;
    int c = flat >> 7;
    int t = (flat >> 5) & 3;
    int f = flat & 31;
    lds[c * 133 + t * 33 + f] =
        x[(((size_t)b * 64 + c) * 500 + t0 + t) * 32 + f];
  }
  __syncthreads();
  const int w = tid >> 6, l = tid & 63;
  #pragma unroll
  for (int rr = 0; rr < 8; rr++) {
    int row = w * 8 + rr;            // 0..31 = (g,t)
    int g = row >> 2, t = row & 3;
    f16x4 v;
    #pragma unroll
    for (int e = 0; e < 4; e++) {
      int i = l * 4 + e;             // i = gf*64 + c
      int gf = i >> 6, c = i & 63;
      v[e] = (f16)lds[c * 133 + t * 33 + g * 4 + gf];
    }
    *(f16x4*)&xi[((size_t)g * 8000 + (size_t)b * 500 + t0 + t) * 256 + l * 4] = v;
  }
}

// ---------------------------------------------------------------------------
// pack W_ih: fp32 -> f16, same layout [G][768][256]
// ---------------------------------------------------------------------------
__global__ void k_pack_wih(const float* __restrict__ w, f16* __restrict__ wh) {
  size_t i0 = ((size_t)blockIdx.x * 256 + threadIdx.x) * 8;
  f32x4 a = *(const f32x4*)(w + i0);
  f32x4 b = *(const f32x4*)(w + i0 + 4);
  f16x8 v;
  v[0]=(f16)a[0]; v[1]=(f16)a[1]; v[2]=(f16)a[2]; v[3]=(f16)a[3];
  v[4]=(f16)b[0]; v[5]=(f16)b[1]; v[6]=(f16)b[2]; v[7]=(f16)b[3];
  *(f16x8*)(wh + i0) = v;
}

// ---------------------------------------------------------------------------
// pack W_hh into per-thread register layout for k_recur (512 threads):
// wp[((g*48 + j)*512 + tid)*8 + e], j = q*16 + kb:
//   = W_hh[g][q*256 + (tid>>1)][(tid&1)*128 + kb*8 + e]
// ---------------------------------------------------------------------------
__global__ void k_pack_whh(const float* __restrict__ w, f16* __restrict__ wp) {
  const int j = blockIdx.x;    // 0..47
  const int g = blockIdx.y;    // 0..7
  const int tid = threadIdx.x; // 0..511
  const int q = j >> 4, kb = j & 15;
  const int row = q * 256 + (tid >> 1);
  const int k0  = (tid & 1) * 128 + kb * 8;
  const float* src = w + ((size_t)g * 768 + row) * 256 + k0;
  f16x8 v;
  #pragma unroll
  for (int e = 0; e < 8; e++) v[e] = (f16)src[e];
  *(f16x8*)&wp[(((size_t)g * 48 + j) * 512 + tid) * 8] = v;
}

// ---------------------------------------------------------------------------
// ih GEMM: per g, C[m][o] = sum_i xi[m][i] * Wih[o][i] + bias_ih[o]
// tile M=64 x N=128, BK=64, 4 waves, mfma_f32_16x16x32_f16, XOR-swizzled LDS.
// ---------------------------------------------------------------------------
__global__ __launch_bounds__(256) void k_gemm(const f16* __restrict__ xi,
                                              const f16* __restrict__ wih,
                                              const float* __restrict__ bias,
                                              f16* __restrict__ ih) {
  const int mt = blockIdx.x;   // 0..124
  const int nt = blockIdx.y;   // 0..5
  const int g  = blockIdx.z;   // 0..7
  const int tid = threadIdx.x;
  const int w = tid >> 6, l = tid & 63;
  __shared__ __align__(16) f16 Als[64 * 64];
  __shared__ __align__(16) f16 Bls[128 * 64];
  f32x4 zero = {0.f, 0.f, 0.f, 0.f};
  f32x4 acc[4][2];
  #pragma unroll
  for (int mi = 0; mi < 4; mi++)
    #pragma unroll
    for (int ni = 0; ni < 2; ni++) acc[mi][ni] = zero;

  const int arow = tid >> 2, aq = tid & 3;
  const int brow = tid >> 1, bq = tid & 1;
  for (int kk = 0; kk < 4; kk++) {
    const f16* asrc = xi + ((size_t)g * 8000 + mt * 64 + arow) * 256 + kk * 64 + aq * 16;
    f16x8 a0 = *(const f16x8*)asrc;
    f16x8 a1 = *(const f16x8*)(asrc + 8);
    *(f16x8*)&Als[arow * 64 + ((aq * 2 + 0) ^ (arow & 7)) * 8] = a0;
    *(f16x8*)&Als[arow * 64 + ((aq * 2 + 1) ^ (arow & 7)) * 8] = a1;
    const f16* bsrc = wih + ((size_t)g * 768 + nt * 128 + brow) * 256 + kk * 64 + bq * 32;
    #pragma unroll
    for (int jj = 0; jj < 4; jj++) {
      f16x8 v = *(const f16x8*)(bsrc + jj * 8);
      *(f16x8*)&Bls[brow * 64 + ((bq * 4 + jj) ^ (brow & 7)) * 8] = v;
    }
    __syncthreads();
    #pragma unroll
    for (int ks = 0; ks < 2; ks++) {
      f16x8 af[4], bf[2];
      #pragma unroll
      for (int mi = 0; mi < 4; mi++) {
        int r = mi * 16 + (l & 15);
        af[mi] = *(const f16x8*)&Als[r * 64 + ((ks * 4 + (l >> 4)) ^ (r & 7)) * 8];
      }
      #pragma unroll
      for (int ni = 0; ni < 2; ni++) {
        int r = w * 32 + ni * 16 + (l & 15);
        bf[ni] = *(const f16x8*)&Bls[r * 64 + ((ks * 4 + (l >> 4)) ^ (r & 7)) * 8];
      }
      #pragma unroll
      for (int mi = 0; mi < 4; mi++)
        #pragma unroll
        for (int ni = 0; ni < 2; ni++)
          acc[mi][ni] = __builtin_amdgcn_mfma_f32_16x16x32_f16(af[mi], bf[ni], acc[mi][ni], 0, 0, 0);
    }
    __syncthreads();
  }
  #pragma unroll
  for (int ni = 0; ni < 2; ni++) {
    int col = nt * 128 + w * 32 + ni * 16 + (l & 15);
    float bs = bias[g * 768 + col];
    #pragma unroll
    for (int mi = 0; mi < 4; mi++) {
      int m0 = mt * 64 + mi * 16 + (l >> 4) * 4;
      #pragma unroll
      for (int e = 0; e < 4; e++) {
        ih[((size_t)g * 8000 + m0 + e) * 768 + col] = (f16)(acc[mi][ni][e] + bs);
      }
    }
  }
}

// ---------------------------------------------------------------------------
// recurrence v3: one block (512 thr, 8 waves) per (b,g) chain, VALU dot2 path.
// Thread (r2=tid>>1, kc=tid&1) owns gate rows {r2, 256+r2, 512+r2} over
// K-half kc*128..+128: 48 f16x8 weights = 192 resident VGPRs, zero spill.
// Reduce: single __shfl_xor(1) per gate (partner = adjacent lane, same wave).
// h double-buffered in LDS -> one barrier per step.
// ---------------------------------------------------------------------------
__global__ __launch_bounds__(512, 2) void k_recur(const f16* __restrict__ ih,
                                                  const f16* __restrict__ wp,
                                                  const float* __restrict__ bias_hh,
                                                  f16* __restrict__ hs,
                                                  float* __restrict__ hlast) {
  const int g = blockIdx.x;    // 0..7
  const int b = blockIdx.y;    // 0..15
  const int tid = threadIdx.x;
  const int r2 = tid >> 1;     // output row 0..255
  const int kc = tid & 1;      // k half
  __shared__ __align__(16) f16 hsm[2][256];

  // 48 weight fragments, fully register-resident
  f16x8 wv[48];
  {
    const f16x8* wsrc = (const f16x8*)wp + (size_t)g * 48 * 512;
    #pragma unroll
    for (int j = 0; j < 48; j++) wv[j] = wsrc[(size_t)j * 512 + tid];
  }

  const float bh0 = bias_hh[g * 768 + r2];
  const float bh1 = bias_hh[g * 768 + 256 + r2];
  const float bh2 = bias_hh[g * 768 + 512 + r2];
  const f16* ihb = ih + ((size_t)g * 8000 + (size_t)b * 500) * 768;
  f16* hsp = hs + (size_t)(b * 8 + g) * 500 * 256;
  float hreg = 0.f;
  f16 c0 = ihb[r2], c1 = ihb[256 + r2], c2 = ihb[512 + r2];
  if (tid < 256) hsm[0][tid] = (f16)0.f;
  __syncthreads();

  int cur = 0;
  for (int t = 0; t < 500; t++) {
    // prefetch next step's ih (latency hidden under dot phase)
    f16 n0 = c0, n1 = c1, n2 = c2;
    if (t + 1 < 500) {
      const f16* p = ihb + (size_t)(t + 1) * 768;
      n0 = p[r2]; n1 = p[256 + r2]; n2 = p[512 + r2];
    }
    // dot phase: 48 dot8 against h broadcast from LDS (incremental h reads)
    float a0 = 0.f, a1 = 0.f, a2 = 0.f;
    const f16x8* hv = (const f16x8*)&hsm[cur][kc * 128];
    #pragma unroll
    for (int kb = 0; kb < 16; kb++) {
      f16x8 h8 = hv[kb];
      a0 = dot8(wv[kb],      h8, a0);
      a1 = dot8(wv[16 + kb], h8, a1);
      a2 = dot8(wv[32 + kb], h8, a2);
    }
    // pairwise reduce across the two k-halves
    a0 += __shfl_xor(a0, 1, 64);
    a1 += __shfl_xor(a1, 1, 64);
    a2 += __shfl_xor(a2, 1, 64);
    // gates (computed redundantly by both lanes of the pair)
    float r = 1.f / (1.f + __expf(-((float)c0 + a0 + bh0)));
    float z = 1.f / (1.f + __expf(-((float)c1 + a1 + bh1)));
    float nx = (float)c2 + r * (a2 + bh2);
    float n = 2.f / (1.f + __expf(-2.f * nx)) - 1.f;
    float hn = (1.f - z) * n + z * hreg;
    hreg = hn;
    if (kc == 0) {
      hsm[cur ^ 1][r2] = (f16)hn;
      hsp[(size_t)t * 256 + r2] = (f16)hn;
    }
    __syncthreads();
    cur ^= 1;
    c0 = n0; c1 = n1; c2 = n2;
  }
  if (kc == 0) hlast[(size_t)(b * 8 + g) * 256 + r2] = hreg;
}

// ---------------------------------------------------------------------------
// un-transpose: hs f16 [b*8+g][t][o] -> out fp32 [b][och][t][f], f=g*4+gf, o=gf*64+och
// ---------------------------------------------------------------------------
__global__ void k_untr(const f16* __restrict__ hs, float* __restrict__ out) {
  const int tc = blockIdx.x;   // 0..62 (8 t each, tail 4)
  const int b  = blockIdx.y;   // 0..15
  const int t0 = tc * 8;
  const int tid = threadIdx.x; // 256
  __shared__ __align__(16) f16 lds[8 * 8 * 260];  // [(tt*8+g)*260 + o]
  {
    const int row = tid >> 2, q = tid & 3;  // row: 64 = (g,tt)
    const int g = row >> 3, tt = row & 7;
    if (t0 + tt < 500) {
      const f16* src = hs + (((size_t)b * 8 + g) * 500 + t0 + tt) * 256 + q * 64;
      #pragma unroll
      for (int jj = 0; jj < 16; jj++) {
        *(f16x4*)&lds[(tt * 8 + g) * 260 + q * 64 + jj * 4] = *(const f16x4*)(src + jj * 4);
      }
    }
  }
  __syncthreads();
  const int w = tid >> 6, l = tid & 63;
  const int tt2 = w * 2 + (l >> 5);
  const int f = l & 31;
  const int gg = f >> 2, gf = f & 3;
  if (t0 + tt2 < 500) {
    float* dst = out + (((size_t)b * 64) * 500 + t0 + tt2) * 32 + f;
    const f16* srcl = &lds[(tt2 * 8 + gg) * 260 + gf * 64];
    #pragma unroll 4
    for (int och = 0; och < 64; och++) {
      dst[(size_t)och * 500 * 32] = (float)srcl[och];
    }
  }
}

// ---------------------------------------------------------------------------
extern "C" void kernel_launch(void* const* d_in, const int* in_sizes, int n_in,
                              void* d_out, int out_size, void* d_ws, size_t ws_size,
                              hipStream_t stream) {
  const float* x   = (const float*)d_in[0];
  const float* wih = (const float*)d_in[1];
  const float* whh = (const float*)d_in[2];
  const float* bih = (const float*)d_in[3];
  const float* bhh = (const float*)d_in[4];
  float* out   = (float*)d_out;
  float* hlast = out + 16384000;   // B*64*T*F

  char* ws = (char*)d_ws;
  f16* ih_h  = (f16*)(ws);                 //  98,304,000 B : [8][8000][768]
  f16* xi_h  = (f16*)(ws + 98304000);      //  32,768,000 B : [8][8000][256]
  f16* wih_h = (f16*)(ws + 131072000);     //   3,145,728 B : [8][768][256]
  f16* whh_p = (f16*)(ws + 134217728);     //   3,145,728 B : packed per-thread
  f16* hs_h  = (f16*)(ws + 137363456);     //  32,768,000 B : [128][500][256]

  k_pack_x  <<<dim3(125, 16), 256, 0, stream>>>(x, xi_h);
  k_pack_wih<<<768, 256, 0, stream>>>(wih, wih_h);
  k_pack_whh<<<dim3(48, 8), 512, 0, stream>>>(whh, whh_p);
  k_gemm    <<<dim3(125, 6, 8), 256, 0, stream>>>(xi_h, wih_h, bih, ih_h);
  k_recur   <<<dim3(8, 16), 512, 0, stream>>>(ih_h, whh_p, bhh, hs_h, hlast);
  k_untr    <<<dim3(63, 16), 256, 0, stream>>>(hs_h, out);
}